// Round 6
// baseline (415.002 us; speedup 1.0000x reference)
//
#include <hip/hip_runtime.h>

#define NA 250000
#define NB 500000
#define NG 50000
#define DD 64
#define EA_N 1000000
#define EG_N 500000
#define FTC 320           // 5*64
#define NSEG (2 * NB)     // [0,NB) = a2b counts, [NB,2NB) = g2b counts
#define SCAN_BLK 1024
#define NSCAN_BLKS ((NSEG + SCAN_BLK - 1) / SCAN_BLK)  // 977

#define EDGE4_BLKS (((EA_N + EG_N) / 4 + 255) / 256)   // 1465
#define COPYA_BLKS 1024
#define COPYG_BLKS 128
#define BOND_BLKS (NB / 32)   // 32 bonds per 256-thread block (16 lanes/bond, 2 bonds/group)

// native clang vector types — required by __builtin_nontemporal_*
typedef float vf4 __attribute__((ext_vector_type(4)));
typedef int   vi4 __attribute__((ext_vector_type(4)));

// ---------------- helpers ----------------

__device__ __forceinline__ float4 f4add(float4 a, float4 b) {
    return make_float4(a.x + b.x, a.y + b.y, a.z + b.z, a.w + b.w);
}
__device__ __forceinline__ float4 f4max(float4 a, float4 b) {
    return make_float4(fmaxf(a.x, b.x), fmaxf(a.y, b.y),
                       fmaxf(a.z, b.z), fmaxf(a.w, b.w));
}
__device__ __forceinline__ float4 f4scale(float4 a, float s) {
    return make_float4(a.x * s, a.y * s, a.z * s, a.w * s);
}
__device__ __forceinline__ float4 ntload4(const float4* p) {
    vf4 v = __builtin_nontemporal_load((const vf4*)p);
    return make_float4(v.x, v.y, v.z, v.w);
}
__device__ __forceinline__ void ntstore4(float4 a, float4* p) {
    vf4 v = {a.x, a.y, a.z, a.w};
    __builtin_nontemporal_store(v, (vf4*)p);
}
__device__ __forceinline__ vi4 ntload_i4(const int* p) {
    return __builtin_nontemporal_load((const vi4*)p);
}

// ---------------- phase 1: count + overlapped pass-through copies ----------------
// blocks [0, EDGE4_BLKS): degree counting (atomic, latency-bound)
// blocks [EDGE4_BLKS, +COPYA_BLKS): atom copy (BW-bound, overlaps)
// remaining: global copy

__global__ __launch_bounds__(256) void count_copy_kernel(
    const int* __restrict__ a2b_dst, const int* __restrict__ g2b_dst,
    int* __restrict__ cnt,
    const float4* __restrict__ atom4, float4* __restrict__ out_atom4,
    const float4* __restrict__ glob4, float4* __restrict__ out_glob4) {
    int bid = blockIdx.x;
    if (bid < EDGE4_BLKS) {
        int i = bid * blockDim.x + threadIdx.x;
        int stride = EDGE4_BLKS * blockDim.x;
        const int totalA = EA_N / 4;
        const int total = (EA_N + EG_N) / 4;
        for (; i < total; i += stride) {
            if (i < totalA) {
                vi4 d = ntload_i4(a2b_dst + 4 * i);
                atomicAdd(&cnt[d.x], 1);
                atomicAdd(&cnt[d.y], 1);
                atomicAdd(&cnt[d.z], 1);
                atomicAdd(&cnt[d.w], 1);
            } else {
                vi4 d = ntload_i4(g2b_dst + 4 * (i - totalA));
                atomicAdd(&cnt[NB + d.x], 1);
                atomicAdd(&cnt[NB + d.y], 1);
                atomicAdd(&cnt[NB + d.z], 1);
                atomicAdd(&cnt[NB + d.w], 1);
            }
        }
    } else if (bid < EDGE4_BLKS + COPYA_BLKS) {
        long long n4 = (long long)NA * DD / 4;
        long long i = (long long)(bid - EDGE4_BLKS) * 256 + threadIdx.x;
        long long stride = (long long)COPYA_BLKS * 256;
        for (; i < n4; i += stride) {
            float4 v = ntload4(&atom4[i]);
            ntstore4(v, &out_atom4[i]);
        }
    } else {
        long long n4 = (long long)NG * DD / 4;
        long long i = (long long)(bid - EDGE4_BLKS - COPYA_BLKS) * 256 + threadIdx.x;
        long long stride = (long long)COPYG_BLKS * 256;
        for (; i < n4; i += stride) {
            float4 v = ntload4(&glob4[i]);
            ntstore4(v, &out_glob4[i]);
        }
    }
}

// ---------------- scan ----------------

__global__ void scan1_kernel(const int* __restrict__ cnt,
                             int* __restrict__ offs,
                             int* __restrict__ bsum) {
    __shared__ int sm[SCAN_BLK];
    int tid = threadIdx.x;
    int idx = blockIdx.x * SCAN_BLK + tid;
    int v = (idx < NSEG) ? cnt[idx] : 0;
    sm[tid] = v;
    __syncthreads();
    for (int off = 1; off < SCAN_BLK; off <<= 1) {
        int t = (tid >= off) ? sm[tid - off] : 0;
        __syncthreads();
        sm[tid] += t;
        __syncthreads();
    }
    if (idx < NSEG) offs[idx] = sm[tid] - v;
    if (tid == SCAN_BLK - 1) bsum[blockIdx.x] = sm[tid];
}

// merged scan2+scan3: each block computes its prefix base by tree-reducing
// bsum[0..bid), then offsets its slice and initializes the cursor.
__global__ void scan23_kernel(int* __restrict__ offs,
                              const int* __restrict__ bsum,
                              int* __restrict__ cursor) {
    __shared__ int red[SCAN_BLK];
    int tid = threadIdx.x;
    int bid = blockIdx.x;
    red[tid] = (tid < bid) ? bsum[tid] : 0;   // bid <= 976 < 1024
    __syncthreads();
    for (int off = SCAN_BLK / 2; off > 0; off >>= 1) {
        if (tid < off) red[tid] += red[tid + off];
        __syncthreads();
    }
    int base = red[0];
    int idx = bid * SCAN_BLK + tid;
    if (idx < NSEG) {
        int o = offs[idx] + base;
        offs[idx] = o;
        cursor[idx] = o;
    }
    if (bid == 0 && tid == 0) offs[NSEG] = EA_N + EG_N;
}

// ---------------- fill ----------------

__global__ void fill_kernel(const int* __restrict__ a2b_src,
                            const int* __restrict__ a2b_dst,
                            const int* __restrict__ g2b_src,
                            const int* __restrict__ g2b_dst,
                            int* __restrict__ cursor,
                            int* __restrict__ esrc) {
    int i = blockIdx.x * blockDim.x + threadIdx.x;
    int stride = gridDim.x * blockDim.x;
    const int totalA = EA_N / 4;
    const int total = (EA_N + EG_N) / 4;
    for (; i < total; i += stride) {
        vi4 d, s;
        int base;
        if (i < totalA) {
            d = ntload_i4(a2b_dst + 4 * i);
            s = ntload_i4(a2b_src + 4 * i);
            base = 0;
        } else {
            d = ntload_i4(g2b_dst + 4 * (i - totalA));
            s = ntload_i4(g2b_src + 4 * (i - totalA));
            base = NB;
        }
        int p0 = atomicAdd(&cursor[base + d.x], 1);
        int p1 = atomicAdd(&cursor[base + d.y], 1);
        int p2 = atomicAdd(&cursor[base + d.z], 1);
        int p3 = atomicAdd(&cursor[base + d.w], 1);
        __builtin_nontemporal_store(s.x, &esrc[p0]);
        __builtin_nontemporal_store(s.y, &esrc[p1]);
        __builtin_nontemporal_store(s.z, &esrc[p2]);
        __builtin_nontemporal_store(s.w, &esrc[p3]);
    }
}

// ---------------- bond mega kernel ----------------
// 32 bonds per 256-thread block; each 16-lane group owns TWO bonds (b0, b0+16)
// and interleaves 4 independent gather chains (2 bonds x {atom, glob}).

__global__ __launch_bounds__(256) void bond_kernel(
    const float4* __restrict__ bond4, const float4* __restrict__ atom4,
    const float4* __restrict__ glob4, const int* __restrict__ offs,
    const int* __restrict__ esrc, float4* __restrict__ ft4) {
    long long b0 = (long long)blockIdx.x * 32 + (threadIdx.x >> 4);
    long long b1 = b0 + 16;
    int q = threadIdx.x & 15;
    int gbase = threadIdx.x & 48;

    // level 0: all 8 offset loads + 2 bond-row loads issue together
    int a00 = offs[b0], a01 = offs[b0 + 1];
    int g00 = offs[NB + b0], g01 = offs[NB + b0 + 1];
    int a10 = offs[b1], a11 = offs[b1 + 1];
    int g10 = offs[NB + b1], g11 = offs[NB + b1 + 1];
    float4 bv0 = ntload4(&bond4[b0 * 16 + q]);
    float4 bv1 = ntload4(&bond4[b1 * 16 + q]);

    int da0 = a01 - a00, dg0 = g01 - g00;
    int da1 = a11 - a10, dg1 = g11 - g10;

    // level 1: all 4 index batches issue together
    int ia0 = (q < da0) ? esrc[a00 + q] : 0;
    int ig0 = (q < dg0) ? esrc[g00 + q] : 0;
    int ia1 = (q < da1) ? esrc[a10 + q] : 0;
    int ig1 = (q < dg1) ? esrc[g10 + q] : 0;

    // level 2: fused gather loop — 4 independent chains per iteration
    float4 sa0 = make_float4(0.f, 0.f, 0.f, 0.f), sa1 = sa0, sg0 = sa0, sg1 = sa0;
    float4 xa0 = make_float4(-INFINITY, -INFINITY, -INFINITY, -INFINITY);
    float4 xa1 = xa0, xg0 = xa0, xg1 = xa0;

    int na0 = min(da0, 16), na1 = min(da1, 16);
    int ng0 = min(dg0, 16), ng1 = min(dg1, 16);
    int nmax = max(max(na0, na1), max(ng0, ng1));
    for (int j = 0; j < nmax; ++j) {
        if (j < na0) {
            int s = __shfl(ia0, gbase + j, 64);
            float4 v = atom4[(long long)s * 16 + q];
            sa0 = f4add(sa0, v); xa0 = f4max(xa0, v);
        }
        if (j < na1) {
            int s = __shfl(ia1, gbase + j, 64);
            float4 v = atom4[(long long)s * 16 + q];
            sa1 = f4add(sa1, v); xa1 = f4max(xa1, v);
        }
        if (j < ng0) {
            int s = __shfl(ig0, gbase + j, 64);
            float4 v = glob4[(long long)s * 16 + q];
            sg0 = f4add(sg0, v); xg0 = f4max(xg0, v);
        }
        if (j < ng1) {
            int s = __shfl(ig1, gbase + j, 64);
            float4 v = glob4[(long long)s * 16 + q];
            sg1 = f4add(sg1, v); xg1 = f4max(xg1, v);
        }
    }
    // rare tails (deg > 16)
    for (int e = a00 + 16; e < a01; ++e) {
        int s = esrc[e];
        float4 v = atom4[(long long)s * 16 + q];
        sa0 = f4add(sa0, v); xa0 = f4max(xa0, v);
    }
    for (int e = a10 + 16; e < a11; ++e) {
        int s = esrc[e];
        float4 v = atom4[(long long)s * 16 + q];
        sa1 = f4add(sa1, v); xa1 = f4max(xa1, v);
    }
    for (int e = g00 + 16; e < g01; ++e) {
        int s = esrc[e];
        float4 v = glob4[(long long)s * 16 + q];
        sg0 = f4add(sg0, v); xg0 = f4max(xg0, v);
    }
    for (int e = g10 + 16; e < g11; ++e) {
        int s = esrc[e];
        float4 v = glob4[(long long)s * 16 + q];
        sg1 = f4add(sg1, v); xg1 = f4max(xg1, v);
    }

    float4 ma0 = f4scale(sa0, da0 ? 1.f / (float)da0 : 0.f);
    float4 ma1 = f4scale(sa1, da1 ? 1.f / (float)da1 : 0.f);
    float4 mg0 = f4scale(sg0, dg0 ? 1.f / (float)dg0 : 0.f);
    float4 mg1 = f4scale(sg1, dg1 ? 1.f / (float)dg1 : 0.f);
    if (!da0) xa0 = make_float4(0.f, 0.f, 0.f, 0.f);
    if (!da1) xa1 = make_float4(0.f, 0.f, 0.f, 0.f);
    if (!dg0) xg0 = make_float4(0.f, 0.f, 0.f, 0.f);
    if (!dg1) xg1 = make_float4(0.f, 0.f, 0.f, 0.f);

    float4* row0 = ft4 + b0 * 80;
    ntstore4(bv0, &row0[q]);
    ntstore4(ma0, &row0[16 + q]);
    ntstore4(xa0, &row0[32 + q]);
    ntstore4(mg0, &row0[48 + q]);
    ntstore4(xg0, &row0[64 + q]);
    float4* row1 = ft4 + b1 * 80;
    ntstore4(bv1, &row1[q]);
    ntstore4(ma1, &row1[16 + q]);
    ntstore4(xa1, &row1[32 + q]);
    ntstore4(mg1, &row1[48 + q]);
    ntstore4(xg1, &row1[64 + q]);
}

// ---------------- launch ----------------

extern "C" void kernel_launch(void* const* d_in, const int* in_sizes, int n_in,
                              void* d_out, int out_size, void* d_ws, size_t ws_size,
                              hipStream_t stream) {
    const float* atom_ft   = (const float*)d_in[0];
    const float* bond_ft   = (const float*)d_in[1];
    const float* global_ft = (const float*)d_in[2];
    const int* a2b_src = (const int*)d_in[3];
    const int* a2b_dst = (const int*)d_in[4];
    const int* g2b_src = (const int*)d_in[5];
    const int* g2b_dst = (const int*)d_in[6];

    float* out = (float*)d_out;
    float* out_atom = out;                            // [NA,64]
    float* out_ft   = out + (long long)NA * DD;       // [NB,320]
    float* out_glob = out_ft + (long long)NB * FTC;   // [NG,64]

    int* ws      = (int*)d_ws;
    int* cnt     = ws;                   // NSEG
    int* offs    = ws + 1000000;         // NSEG+1
    int* cursor  = ws + 2000004;         // NSEG
    int* bsum    = ws + 3000004;         // SCAN_BLK
    int* esrc    = ws + 3001028;         // EA_N+EG_N

    const int BLK = 256;

    (void)hipMemsetAsync(cnt, 0, (size_t)NSEG * sizeof(int), stream);

    count_copy_kernel<<<EDGE4_BLKS + COPYA_BLKS + COPYG_BLKS, BLK, 0, stream>>>(
        a2b_dst, g2b_dst, cnt,
        (const float4*)atom_ft, (float4*)out_atom,
        (const float4*)global_ft, (float4*)out_glob);

    scan1_kernel<<<NSCAN_BLKS, SCAN_BLK, 0, stream>>>(cnt, offs, bsum);
    scan23_kernel<<<NSCAN_BLKS, SCAN_BLK, 0, stream>>>(offs, bsum, cursor);

    fill_kernel<<<EDGE4_BLKS, BLK, 0, stream>>>(
        a2b_src, a2b_dst, g2b_src, g2b_dst, cursor, esrc);

    bond_kernel<<<BOND_BLKS, BLK, 0, stream>>>(
        (const float4*)bond_ft, (const float4*)atom_ft,
        (const float4*)global_ft, offs, esrc, (float4*)out_ft);
}